// Round 1
// baseline (591.347 us; speedup 1.0000x reference)
//
#include <hip/hip_runtime.h>

// SubsetOperator: khot = sum_{k=1..16} softmax(s_k), s_{k+1} = s_k + log(max(1-softmax(s_k), tiny))
// Shapes: scores, g: [B=4096, N=8192] fp32. One block per row, 1024 threads,
// 8 elements/thread held in registers across all 16 iterations.
// Compute-bound on v_exp_f32/v_log_f32 (~537M of each); memory floor 61us.

constexpr int N_COLS  = 8192;
constexpr int THREADS = 1024;
constexpr int PER     = N_COLS / THREADS;   // 8 elements per thread
constexpr int KITER   = 16;
constexpr float EPSILON = 1.17549435e-38f;  // np.finfo(np.float32).tiny

__global__ __launch_bounds__(THREADS)
void subset_op_kernel(const float* __restrict__ scores,
                      const float* __restrict__ gnoise,
                      float* __restrict__ out)
{
    const int row  = blockIdx.x;
    const int t    = threadIdx.x;
    const int wave = t >> 6;
    const int lane = t & 63;
    const size_t base = (size_t)row * N_COLS;

    const float4* s4 = (const float4*)(scores + base);
    const float4* g4 = (const float4*)(gnoise + base);
    float4*       o4 = (float4*)(out + base);

    float s[PER], kh[PER], e[PER];

    // Load + s0 = scores + g. Lane t takes float4 at (c*1024 + t): 16B/lane coalesced.
    #pragma unroll
    for (int c = 0; c < PER / 4; ++c) {
        float4 a = s4[c * THREADS + t];
        float4 b = g4[c * THREADS + t];
        s[c*4 + 0] = a.x + b.x;
        s[c*4 + 1] = a.y + b.y;
        s[c*4 + 2] = a.z + b.z;
        s[c*4 + 3] = a.w + b.w;
        kh[c*4 + 0] = 0.0f; kh[c*4 + 1] = 0.0f;
        kh[c*4 + 2] = 0.0f; kh[c*4 + 3] = 0.0f;
    }

    __shared__ float redmax[16];   // one partial per wave
    __shared__ float redsum[16];

    for (int it = 0; it < KITER; ++it) {
        // ---- row max ----
        float m = s[0];
        #pragma unroll
        for (int j = 1; j < PER; ++j) m = fmaxf(m, s[j]);
        #pragma unroll
        for (int off = 32; off > 0; off >>= 1)
            m = fmaxf(m, __shfl_xor(m, off, 64));
        if (lane == 0) redmax[wave] = m;
        __syncthreads();                       // barrier 1
        m = redmax[0];
        #pragma unroll
        for (int k = 1; k < 16; ++k) m = fmaxf(m, redmax[k]);  // broadcast reads

        // ---- row sum of exp ----
        float z = 0.0f;
        #pragma unroll
        for (int j = 0; j < PER; ++j) {
            e[j] = __expf(s[j] - m);           // v_exp_f32
            z += e[j];
        }
        #pragma unroll
        for (int off = 32; off > 0; off >>= 1)
            z += __shfl_xor(z, off, 64);
        if (lane == 0) redsum[wave] = z;
        __syncthreads();                       // barrier 2
        z = redsum[0];
        #pragma unroll
        for (int k = 1; k < 16; ++k) z += redsum[k];

        // ---- update ----
        const float inv = 1.0f / z;
        #pragma unroll
        for (int j = 0; j < PER; ++j) {
            float oh = e[j] * inv;             // onehot (TAU = 1)
            kh[j] += oh;
            s[j] += __logf(fmaxf(1.0f - oh, EPSILON));  // v_log_f32
        }
        // Cross-iteration LDS hazard analysis: redmax writes (after barrier 2 of
        // prev iter via loop back-edge... specifically reads of redmax happen
        // between barrier1_i and barrier2_i; next write is after barrier2_i.
        // redsum reads happen between barrier2_i and barrier1_{i+1}; next write
        // after barrier1_{i+1}. No extra barriers needed.
    }

    #pragma unroll
    for (int c = 0; c < PER / 4; ++c) {
        float4 v;
        v.x = kh[c*4 + 0]; v.y = kh[c*4 + 1];
        v.z = kh[c*4 + 2]; v.w = kh[c*4 + 3];
        o4[c * THREADS + t] = v;
    }
}

extern "C" void kernel_launch(void* const* d_in, const int* in_sizes, int n_in,
                              void* d_out, int out_size, void* d_ws, size_t ws_size,
                              hipStream_t stream)
{
    const float* scores = (const float*)d_in[0];
    const float* gnoise = (const float*)d_in[1];
    float* out = (float*)d_out;
    const int rows = in_sizes[0] / N_COLS;     // 4096

    subset_op_kernel<<<rows, THREADS, 0, stream>>>(scores, gnoise, out);
}

// Round 2
// 332.657 us; speedup vs baseline: 1.7777x; 1.7777x over previous
//
#include <hip/hip_runtime.h>

// SubsetOperator (relaxed top-K=16), rewritten in exp-space:
//   reference: s += log(max(1-softmax(s), eps)) repeated 16x, khot = sum softmax
//   identity:  softmax(s + log(mask)) = normalize(exp(s) * mask)
//   so maintain e = exp(s0 - rowmax) and iterate e *= max(1 - e/z, eps).
// No exp/log in the loop -> ~6 full-rate VALU ops per element-iteration.
// One block per row; 512 threads x 16 elements/thread in registers.

constexpr int N_COLS  = 8192;
constexpr int THREADS = 512;
constexpr int PER     = N_COLS / THREADS;   // 16 elements per thread
constexpr int NWAVES  = THREADS / 64;       // 8 waves
constexpr int KITER   = 16;
constexpr float EPSILON = 1.17549435e-38f;  // np.finfo(np.float32).tiny

__global__ __launch_bounds__(THREADS)
void subset_op_kernel(const float* __restrict__ scores,
                      const float* __restrict__ gnoise,
                      float* __restrict__ out)
{
    const int t    = threadIdx.x;
    const int wave = t >> 6;
    const int lane = t & 63;
    const size_t base = (size_t)blockIdx.x * N_COLS;

    const float4* s4 = (const float4*)(scores + base);
    const float4* g4 = (const float4*)(gnoise + base);
    float4*       o4 = (float4*)(out + base);

    float e[PER], kh[PER];

    // Load, s0 = scores + g (kept temporarily in e[])
    #pragma unroll
    for (int c = 0; c < PER / 4; ++c) {
        float4 a = s4[c * THREADS + t];
        float4 b = g4[c * THREADS + t];
        e[c*4 + 0] = a.x + b.x;
        e[c*4 + 1] = a.y + b.y;
        e[c*4 + 2] = a.z + b.z;
        e[c*4 + 3] = a.w + b.w;
    }

    __shared__ float redm[NWAVES];
    __shared__ float red[2][NWAVES];

    // ---- one-time row max (stability shift; max only decreases across
    // iterations since log(mask) <= 0, so a single shift never overflows) ----
    float m = e[0];
    #pragma unroll
    for (int j = 1; j < PER; ++j) m = fmaxf(m, e[j]);
    #pragma unroll
    for (int off = 32; off > 0; off >>= 1)
        m = fmaxf(m, __shfl_xor(m, off, 64));
    if (lane == 0) redm[wave] = m;
    __syncthreads();
    {
        float4 r0 = ((const float4*)redm)[0];
        float4 r1 = ((const float4*)redm)[1];
        m = fmaxf(fmaxf(fmaxf(r0.x, r0.y), fmaxf(r0.z, r0.w)),
                  fmaxf(fmaxf(r1.x, r1.y), fmaxf(r1.z, r1.w)));
    }

    // ---- e = exp(s0 - m), once; kh = 0 ----
    #pragma unroll
    for (int j = 0; j < PER; ++j) {
        e[j] = __expf(e[j] - m);
        kh[j] = 0.0f;
    }

    // ---- 16 iterations, transcendental-free ----
    // Barrier safety: iteration i writes red[i&1], barriers, reads red[i&1].
    // Iteration i+1 writes red[(i+1)&1] (other buffer) so a fast wave's write
    // cannot race a slow wave's read; the first write to red[i&1] again is at
    // iteration i+2, which is after barrier i+1, which every wave only passes
    // after finishing its iteration-i reads. One barrier per iteration.
    // (First loop write to red[0] races nothing: redm is a separate array.)
    for (int it = 0; it < KITER; ++it) {
        // pairwise partial sum (short dep chain)
        float z = 0.0f;
        #pragma unroll
        for (int j = 0; j < PER; ++j) z += e[j];
        #pragma unroll
        for (int off = 32; off > 0; off >>= 1)
            z += __shfl_xor(z, off, 64);
        if (lane == 0) red[it & 1][wave] = z;
        __syncthreads();
        {
            float4 r0 = ((const float4*)red[it & 1])[0];
            float4 r1 = ((const float4*)red[it & 1])[1];
            z = (r0.x + r0.y) + (r0.z + r0.w) + (r1.x + r1.y) + (r1.z + r1.w);
        }

        const float inv = __builtin_amdgcn_rcpf(z);   // v_rcp_f32, ~1 ulp
        #pragma unroll
        for (int j = 0; j < PER; ++j) {
            float oh = e[j] * inv;                    // onehot (TAU = 1)
            kh[j] += oh;
            e[j] *= fmaxf(1.0f - oh, EPSILON);        // s += log(max(1-oh,eps))
        }
    }

    #pragma unroll
    for (int c = 0; c < PER / 4; ++c) {
        float4 v;
        v.x = kh[c*4 + 0]; v.y = kh[c*4 + 1];
        v.z = kh[c*4 + 2]; v.w = kh[c*4 + 3];
        o4[c * THREADS + t] = v;
    }
}

extern "C" void kernel_launch(void* const* d_in, const int* in_sizes, int n_in,
                              void* d_out, int out_size, void* d_ws, size_t ws_size,
                              hipStream_t stream)
{
    const float* scores = (const float*)d_in[0];
    const float* gnoise = (const float*)d_in[1];
    float* out = (float*)d_out;
    const int rows = in_sizes[0] / N_COLS;     // 4096

    subset_op_kernel<<<rows, THREADS, 0, stream>>>(scores, gnoise, out);
}